// Round 22
// baseline (4012.023 us; speedup 1.0000x reference)
//
#include <hip/hip_runtime.h>

typedef unsigned short u16;
typedef unsigned int u32;
typedef unsigned long long u64;
typedef __attribute__((ext_vector_type(4))) float f32x4;
typedef __attribute__((ext_vector_type(8))) short s16x8;

__device__ __forceinline__ float bf2f(u16 u) {
  union { u32 i; float f; } x;
  x.i = ((u32)u) << 16;
  return x.f;
}
__device__ __forceinline__ u16 f2bf(float f) {
  union { float f; u32 i; } u;
  u.f = f;
  u32 r = u.i + 0x7fffu + ((u.i >> 16) & 1u);
  return (u16)(r >> 16);
}

static inline int nblkD(long long n) { return (int)((n + 255) / 256); }

// identifier-named symbol; generic zero-fill
__global__ void HeteroGraphSAGE_52931176955955_kernel(float* p, long long n) {
  long long i = (long long)blockIdx.x * 256 + threadIdx.x;
  if (i < n) p[i] = 0.0f;
}

// ---------------- weight prep: 25 bf16 W^T mats (n-major) ----------------
__global__ void g_wprep(const float* Wl, const float* Wr, u16* wt, int total) {
  int idx = blockIdx.x * 256 + threadIdx.x;
  if (idx >= total) return;
  int w = idx >> 14;
  int r = idx & 16383;
  int n = r >> 7, k = r & 127;
  float v;
  if (w < 11) v = Wl[w * 16384 + k * 128 + n];
  else if (w < 22) v = Wr[(w - 11) * 16384 + k * 128 + n];
  else {
    int a = (w == 22) ? 2 : (w == 23) ? 6 : 7;
    int b = (w == 22) ? 4 : (w == 23) ? 8 : 10;
    v = Wr[a * 16384 + k * 128 + n] + Wr[b * 16384 + k * 128 + n];
  }
  wt[idx] = f2bf(v);
}

__global__ void g_bprep(const float* bL, float* cb) {
  int c = threadIdx.x;  // 128
  cb[c]       = bL[2 * 128 + c] + bL[4 * 128 + c];
  cb[128 + c] = bL[6 * 128 + c] + bL[8 * 128 + c];
  cb[256 + c] = bL[7 * 128 + c] + bL[10 * 128 + c];
}

__global__ void g_cvt(const float* x, u16* o, long long n4) {
  long long i = (long long)blockIdx.x * 256 + threadIdx.x;
  if (i >= n4) return;
  f32x4 v = *(const f32x4*)(x + (i << 2));
  u64 p = ((u64)f2bf(v.x)) | (((u64)f2bf(v.y)) << 16) |
          (((u64)f2bf(v.z)) << 32) | (((u64)f2bf(v.w)) << 48);
  *(u64*)(o + (i << 2)) = p;
}

// ---------------- CSR build ----------------
__global__ void g_deg(const int* e, int E, int* deg) {
  int w = blockIdx.x * 256 + threadIdx.x;
  if (w >= E) return;
  atomicAdd(deg + e[E + w], 1);
}

__global__ void g_bsum(const int* deg, int n, int C, int* bsum) {
  __shared__ int ws[4];
  int b = blockIdx.x, tid = threadIdx.x;
  int lane = tid & 63, wv = tid >> 6;
  int lo = b * C, hi = lo + C; if (hi > n) hi = n;
  int s = 0;
  for (int i = lo + tid; i < hi; i += 256) s += deg[i];
  for (int o = 32; o > 0; o >>= 1) s += __shfl_down(s, o);
  if (lane == 0) ws[wv] = s;
  __syncthreads();
  if (tid == 0) bsum[b] = ws[0] + ws[1] + ws[2] + ws[3];
}

__global__ void g_scan_write(const int* deg, int n, int C, const int* bsum,
                             int* rp, int* cur) {
  __shared__ int ws[4];
  __shared__ int bc;
  int b = blockIdx.x, tid = threadIdx.x;
  int lane = tid & 63, wv = tid >> 6;

  int v = bsum[tid];
  int s = (tid < b) ? v : 0;
  for (int o = 32; o > 0; o >>= 1) s += __shfl_down(s, o);
  if (lane == 0) ws[wv] = s;
  __syncthreads();
  if (tid == 0) bc = ws[0] + ws[1] + ws[2] + ws[3];
  __syncthreads();
  int base = bc;

  if (b == 0) {
    __syncthreads();
    int t = v;
    for (int o = 32; o > 0; o >>= 1) t += __shfl_down(t, o);
    if (lane == 0) ws[wv] = t;
    __syncthreads();
    if (tid == 0) rp[n] = ws[0] + ws[1] + ws[2] + ws[3];
  }

  int lo = b * C, hi = lo + C; if (hi > n) hi = n;
  for (int t0 = lo; t0 < hi; t0 += 256) {
    int i = t0 + tid;
    int d = (i < hi) ? deg[i] : 0;
    int x = d;
    for (int o = 1; o < 64; o <<= 1) {
      int t = __shfl_up(x, o);
      if (lane >= o) x += t;
    }
    __syncthreads();
    if (lane == 63) ws[wv] = x;
    __syncthreads();
    int wadd = 0;
    if (wv > 0) wadd += ws[0];
    if (wv > 1) wadd += ws[1];
    if (wv > 2) wadd += ws[2];
    int excl = x + wadd - d;
    if (i < hi) {
      rp[i] = base + excl;
      cur[i] = base + excl;
    }
    base += ws[0] + ws[1] + ws[2] + ws[3];
    __syncthreads();
  }
}

__global__ void g_fill(const int* e, int E, int* cur, int* col) {
  int w = blockIdx.x * 256 + threadIdx.x;
  if (w >= E) return;
  int s = e[w];
  int d = e[E + w];
  col[atomicAdd(cur + d, 1)] = s;
}

// ---------------- fused (dual-edge) gather + transform + MFMA SAGE ----------------
// Edge-parallel gather: task=(edge,chunk); coalesced 16B loads, all independent;
// accumulate raw/relu'd fp32 via LDS atomics; BN transform folded into finalize.
__device__ __forceinline__ void stage_store(u16* sm, int rr, int q, const float* acc) {
  s16x8 o;
#pragma unroll
  for (int e = 0; e < 8; ++e) o[e] = (short)f2bf(acc[e]);
  int byte = (rr << 8) + (q << 4);
  int swz = byte ^ ((rr & 7) << 4);
  *(s16x8*)((char*)sm + swz) = o;
}

__global__ __launch_bounds__(256) void g_sage(
    const int* rpA, const int* colA, const u16* srcA, const float* scshA, const u16* wtlA,
    const int* rpB, const int* colB, const u16* srcB, const float* scshB, const u16* wtlB,
    const void* root, int root_f32, const float* scshR, const u16* wtr,
    const float* bias, void* out, int out_bf, int N, float* partial) {
  extern __shared__ __align__(16) char smem[];
  const int tid = threadIdx.x;
  const int r0 = blockIdx.x * 32;
  const int nA = 1 + (rpB ? 1 : 0);
  float* tileF0 = (float*)smem;
  float* tileF1 = (float*)(smem + 16384);
  u16* smA = (u16*)smem;                          // bf16 tile in-place over tileF0
  u16* smB = (u16*)(smem + 16384);                // in-place over tileF1
  u16* smR = (u16*)(smem + (size_t)nA * 16384);
  int* rps0 = (int*)(smem + (size_t)nA * 16384 + (root ? 8192 : 0));
  int* rps1 = rps0 + 64;
  float* bs = (float*)((char*)rps0 + 512);
  if (partial) bs[tid] = 0.f;

  // stage rp slices (33 entries each)
  if (tid < 33) {
    int r = r0 + tid; if (r > N) r = N;
    rps0[tid] = rpA[r];
  }
  if (rpB && tid >= 64 && tid < 97) {
    int r = r0 + (tid - 64); if (r > N) r = N;
    rps1[tid - 64] = rpB[r];
  }
  // zero fp32 tiles
  for (int i = tid; i < nA * 4096; i += 256) ((float*)smem)[i] = 0.f;
  __syncthreads();

  // ---- edge-parallel gather per region ----
  for (int region = 0; region < nA; ++region) {
    const int* rps = region ? rps1 : rps0;
    const int* col = region ? colB : colA;
    const u16* src = region ? srcB : srcA;
    const bool hasT = (region ? scshB : scshA) != 0;
    float* tf = region ? tileF1 : tileF0;
    int jlo = rps[0];
    int ne = rps[32] - jlo;
    for (int t = tid; t < ne * 16; t += 256) {
      int j = t >> 4, q = t & 15;
      int jj = jlo + j;
      int s = col[jj];
      s16x8 v = *(const s16x8*)(src + (size_t)s * 128 + q * 8);
      int lo = 0, hi = 32;
#pragma unroll
      for (int it = 0; it < 5; ++it) {
        int mid = (lo + hi) >> 1;
        if (rps[mid] <= jj) lo = mid; else hi = mid;
      }
      float* dst = tf + lo * 128 + q * 8;
#pragma unroll
      for (int e = 0; e < 8; ++e) {
        float f = bf2f((u16)v[e]);
        if (hasT) f = fmaxf(f, 0.f);
        atomicAdd(dst + e, f);
      }
    }
  }
  // ---- root staging (direct, 2 tasks/thread) ----
  if (root) {
    for (int i = tid; i < 512; i += 256) {
      int rr = i >> 4, q = i & 15;
      int row = r0 + rr;
      int c0 = q * 8;
      float a[8];
#pragma unroll
      for (int e = 0; e < 8; ++e) a[e] = 0.f;
      if (row < N) {
        if (root_f32) {
          const float* rp_ = (const float*)root + (size_t)row * 128 + c0;
          f32x4 lo = *(const f32x4*)rp_;
          f32x4 hi = *(const f32x4*)(rp_ + 4);
          a[0] = lo.x; a[1] = lo.y; a[2] = lo.z; a[3] = lo.w;
          a[4] = hi.x; a[5] = hi.y; a[6] = hi.z; a[7] = hi.w;
        } else {
          s16x8 v = *(const s16x8*)((const u16*)root + (size_t)row * 128 + c0);
#pragma unroll
          for (int e = 0; e < 8; ++e) a[e] = bf2f((u16)v[e]);
        }
        if (scshR) {
#pragma unroll
          for (int e = 0; e < 8; ++e)
            a[e] = fmaxf(a[e], 0.f) * scshR[c0 + e] + scshR[128 + c0 + e];
        }
      }
      stage_store(smR, rr, q, a);
    }
  }
  __syncthreads();

  // ---- finalize: fp32 tile -> mean/transform -> swizzled bf16 (in place) ----
  {
    const int rr = tid >> 3;
    const int c0 = (tid & 7) * 16;
    for (int region = 0; region < nA; ++region) {
      const float* scsh = region ? scshB : scshA;
      const int* rps = region ? rps1 : rps0;
      const float* tf = region ? tileF1 : tileF0;
      u16* sm = region ? smB : smA;
      int deg = rps[rr + 1] - rps[rr];
      float inv = (deg > 0) ? 1.0f / (float)deg : 0.0f;
      float vr[16];
#pragma unroll
      for (int e = 0; e < 16; ++e) vr[e] = tf[rr * 128 + c0 + e] * inv;
      if (scsh && deg > 0) {
#pragma unroll
        for (int e = 0; e < 16; ++e)
          vr[e] = vr[e] * scsh[c0 + e] + scsh[128 + c0 + e];
      }
      __syncthreads();  // all reads of tf done
#pragma unroll
      for (int h = 0; h < 2; ++h) {
        s16x8 o;
#pragma unroll
        for (int e = 0; e < 8; ++e) o[e] = (short)f2bf(vr[h * 8 + e]);
        int byte = (rr << 8) + ((c0 + h * 8) << 1);
        int swz = byte ^ ((rr & 7) << 4);
        *(s16x8*)((char*)sm + swz) = o;
      }
      __syncthreads();
    }
  }

  // ---- MFMA: wave wv -> row-tile m=wv>>1, col-tiles nq..nq+3 ----
  const int lane = tid & 63;
  const int wv = tid >> 6;
  const int mi = lane & 15;
  const int kg = lane >> 4;
  const int m = wv >> 1;
  const int nq = (wv & 1) * 4;
  const int arow = m * 16 + mi;
  const int abase = arow << 8;
  const int amask = (arow & 7) << 4;

  f32x4 acc4[4];
#pragma unroll
  for (int t = 0; t < 4; ++t) acc4[t] = (f32x4){0.f, 0.f, 0.f, 0.f};

#pragma unroll
  for (int kt = 0; kt < 4; ++kt) {
    int k0 = kt * 32 + kg * 8;
    int off = (abase + (k0 << 1)) ^ amask;
    s16x8 afA = *(const s16x8*)((const char*)smA + off);
    s16x8 afB, afR;
    if (rpB) afB = *(const s16x8*)((const char*)smB + off);
    if (root) afR = *(const s16x8*)((const char*)smR + off);
#pragma unroll
    for (int t = 0; t < 4; ++t) {
      int cr = (nq + t) * 16 + mi;
      s16x8 b = *(const s16x8*)(wtlA + cr * 128 + k0);
      acc4[t] = __builtin_amdgcn_mfma_f32_16x16x32_bf16(afA, b, acc4[t], 0, 0, 0);
      if (rpB) {
        s16x8 b2 = *(const s16x8*)(wtlB + cr * 128 + k0);
        acc4[t] = __builtin_amdgcn_mfma_f32_16x16x32_bf16(afB, b2, acc4[t], 0, 0, 0);
      }
      if (root) {
        s16x8 b3 = *(const s16x8*)(wtr + cr * 128 + k0);
        acc4[t] = __builtin_amdgcn_mfma_f32_16x16x32_bf16(afR, b3, acc4[t], 0, 0, 0);
      }
    }
  }

  // ---- epilogue: C/D col=lane&15, row=(lane>>4)*4+reg [m89]; fused BN stats ----
  int rbase = (lane >> 4) << 2;
#pragma unroll
  for (int t = 0; t < 4; ++t) {
    int c = (nq + t) * 16 + mi;
    float bb = bias[c];
    float s = 0.f, q = 0.f;
#pragma unroll
    for (int reg = 0; reg < 4; ++reg) {
      int row = r0 + m * 16 + rbase + reg;
      if (row < N) {
        size_t o = (size_t)row * 128 + c;
        float v = acc4[t][reg] + bb;
        if (out_bf) ((u16*)out)[o] = f2bf(v);
        else        ((float*)out)[o] = v;
        if (partial) {
          float r = fmaxf(v, 0.f);
          s += r;
          q += r * r;
        }
      }
    }
    if (partial) {
      s += __shfl_xor(s, 16); s += __shfl_xor(s, 32);
      q += __shfl_xor(q, 16); q += __shfl_xor(q, 32);
      if (kg == 0) {
        atomicAdd(&bs[c], s);
        atomicAdd(&bs[128 + c], q);
      }
    }
  }
  if (partial) {
    __syncthreads();
    partial[(size_t)blockIdx.x * 256 + tid] = bs[tid];
  }
}

// ---------------- BN finalize: 2-stage partial reduce ----------------
__global__ void g_bnred(const float* partial, int nb, float* p2) {
  int tid = threadIdx.x;  // 256
  float acc = 0.f;
  for (int blk = blockIdx.x; blk < nb; blk += 64)
    acc += partial[(size_t)blk * 256 + tid];
  p2[(size_t)blockIdx.x * 256 + tid] = acc;
}

__global__ void g_bnfin(const float* p2, const float* g, const float* b,
                        float invN, float* scsh) {
  int c = threadIdx.x;  // 128
  float s = 0.f, q = 0.f;
  for (int blk = 0; blk < 64; ++blk) {
    s += p2[(size_t)blk * 256 + c];
    q += p2[(size_t)blk * 256 + 128 + c];
  }
  float m = s * invN;
  float v = q * invN - m * m;
  float sc = rsqrtf(v + 1e-5f) * g[c];
  scsh[c] = sc;
  scsh[128 + c] = b[c] - m * sc;
}

// ---------------- host ----------------
struct Csr { int* rp; int* col; };

static void build_csr(const int* e, int E, int ndst, Csr c, int* dega, int* cur,
                      int* bsum, hipStream_t st) {
  HeteroGraphSAGE_52931176955955_kernel<<<nblkD(ndst), 256, 0, st>>>((float*)dega, ndst);
  g_deg<<<nblkD(E), 256, 0, st>>>(e, E, dega);
  int C = (ndst + 255) / 256;
  g_bsum<<<256, 256, 0, st>>>(dega, ndst, C, bsum);
  g_scan_write<<<256, 256, 0, st>>>(dega, ndst, C, bsum, c.rp, cur);
  g_fill<<<nblkD(E), 256, 0, st>>>(e, E, cur, c.col);
}

static void bn_vD(int nb, const float* g, const float* b, int n,
                  float* partial, float* p2, float* scsh, hipStream_t st) {
  g_bnred<<<64, 256, 0, st>>>(partial, nb, p2);
  g_bnfin<<<1, 128, 0, st>>>(p2, g, b, 1.0f / (float)n, scsh);
}

static inline int lds_sz(int hasB, int hasRoot) {
  return (1 + hasB) * 16384 + (hasRoot ? 8192 : 0) + 512 + 1024;
}

extern "C" void kernel_launch(void* const* d_in, const int* in_sizes, int n_in,
                              void* d_out, int out_size, void* d_ws, size_t ws_size,
                              hipStream_t stream) {
  const float* x_paper  = (const float*)d_in[0];
  const float* x_author = (const float*)d_in[1];
  const int* e_pp = (const int*)d_in[3];
  const int* e_pa = (const int*)d_in[4];
  const int* e_ap = (const int*)d_in[5];
  const int* e_ai = (const int*)d_in[6];
  const int* e_ia = (const int*)d_in[7];
  const float* Wl  = (const float*)d_in[8];
  const float* bL  = (const float*)d_in[9];
  const float* Wr  = (const float*)d_in[10];
  const float* bng = (const float*)d_in[11];
  const float* bnb = (const float*)d_in[12];

  const int NP = in_sizes[0] / 128;
  const int NA = in_sizes[1] / 128;
  const int NI = in_sizes[2] / 128;
  const int Epp = in_sizes[3] / 2;
  const int Epa = in_sizes[4] / 2;
  const int Eap = in_sizes[5] / 2;
  const int Eai = in_sizes[6] / 2;
  const int Eia = in_sizes[7] / 2;

  const int nbP = (NP + 31) / 32;
  const int nbA = (NA + 31) / 32;
  const int nbI = (NI + 31) / 32;

  // ws (~160 MB)
  char* ws = (char*)d_ws;
  size_t off = 0;
  u16* xp   = (u16*)(ws + off);   off += (size_t)NP * 256;
  u16* h_p1 = (u16*)(ws + off);   off += (size_t)NP * 256;
  u16* h_a1 = (u16*)(ws + off);   off += (size_t)NA * 256;
  u16* wt   = (u16*)(ws + off);   off += (size_t)25 * 16384 * 2;
  Csr cpp; cpp.rp = (int*)(ws + off); off += (size_t)(NP + 1) * 4;
  Csr cpa; cpa.rp = (int*)(ws + off); off += (size_t)(NA + 1) * 4;
  Csr cap; cap.rp = (int*)(ws + off); off += (size_t)(NP + 1) * 4;
  Csr cai; cai.rp = (int*)(ws + off); off += (size_t)(NI + 1) * 4;
  Csr cia; cia.rp = (int*)(ws + off); off += (size_t)(NA + 1) * 4;
  cpp.col = (int*)(ws + off); off += (size_t)Epp * 4;
  cpa.col = (int*)(ws + off); off += (size_t)Epa * 4;
  cap.col = (int*)(ws + off); off += (size_t)Eap * 4;
  cai.col = (int*)(ws + off); off += (size_t)Eai * 4;
  cia.col = (int*)(ws + off); off += (size_t)Eia * 4;
  int* dega = (int*)(ws + off);      off += (size_t)NP * 4;
  int* cur  = (int*)(ws + off);      off += (size_t)NP * 4;
  int* bsum = (int*)(ws + off);      off += 1024;
  float* partial = (float*)(ws + off); off += (size_t)nbP * 1024;
  float* p2    = (float*)(ws + off); off += 64 * 1024;
  float* scsh0 = (float*)(ws + off); off += 1024;
  float* scsh1 = (float*)(ws + off); off += 1024;
  float* scsh2 = (float*)(ws + off); off += 1024;
  float* scsh3 = (float*)(ws + off); off += 1024;
  float* scsh4 = (float*)(ws + off); off += 1024;
  float* cb    = (float*)(ws + off); off += 3 * 512;

  // d_out fp32 regions: p2 | a2 | i2; raw bf16 hiddens parked inside
  float* outp = (float*)d_out;
  float* outa = outp + (size_t)NP * 128;
  float* outi = outa + (size_t)NA * 128;
  u16* h_p0 = (u16*)outp;
  u16* h_a0 = (u16*)outa;
  u16* h_i1 = (u16*)outp + (size_t)NP * 128;

  g_wprep<<<nblkD(25 * 16384), 256, 0, stream>>>(Wl, Wr, wt, 25 * 16384);
  g_bprep<<<1, 128, 0, stream>>>(bL, cb);
  g_cvt<<<nblkD((long long)NP * 32), 256, 0, stream>>>(x_paper, xp, (long long)NP * 32);
  build_csr(e_pp, Epp, NP, cpp, dega, cur, bsum, stream);
  build_csr(e_pa, Epa, NA, cpa, dega, cur, bsum, stream);
  build_csr(e_ap, Eap, NP, cap, dega, cur, bsum, stream);
  build_csr(e_ai, Eai, NI, cai, dega, cur, bsum, stream);
  build_csr(e_ia, Eia, NA, cia, dega, cur, bsum, stream);

  const float* nof = (const float*)0;
  const int* noi = (const int*)0;
  const u16* nou = (const u16*)0;
  float* nop = (float*)0;

#define WT(i) (wt + (size_t)(i) * 16384)

  // ---- Layer 0 (raw hidden + fused BN stats) ----
  g_sage<<<nbP, 256, lds_sz(0, 1), stream>>>(
      cpp.rp, cpp.col, xp, nof, WT(0), noi, noi, nou, nof, nou,
      xp, 0, nof, WT(11), bL + 0 * 128, h_p0, 1, NP, partial);
  bn_vD(nbP, bng + 0 * 128, bnb + 0 * 128, NP, partial, p2, scsh0, stream);
  g_sage<<<nbA, 256, lds_sz(0, 1), stream>>>(
      cpa.rp, cpa.col, xp, nof, WT(1), noi, noi, nou, nof, nou,
      x_author, 1, nof, WT(12), bL + 1 * 128, h_a0, 1, NA, partial);
  bn_vD(nbA, bng + 1 * 128, bnb + 1 * 128, NA, partial, p2, scsh1, stream);

  // ---- Layer 1 ----
  g_sage<<<nbP, 256, lds_sz(1, 1), stream>>>(             // p1 = pp + ap (dual)
      cpp.rp, cpp.col, h_p0, scsh0, WT(2), cap.rp, cap.col, h_a0, scsh1, WT(4),
      h_p0, 0, scsh0, WT(22), cb, h_p1, 1, NP, partial);
  bn_vD(nbP, bng + 2 * 128, bnb + 2 * 128, NP, partial, p2, scsh2, stream);
  g_sage<<<nbA, 256, lds_sz(0, 1), stream>>>(             // a1 = pa
      cpa.rp, cpa.col, h_p0, scsh0, WT(3), noi, noi, nou, nof, nou,
      h_a0, 0, scsh1, WT(14), bL + 3 * 128, h_a1, 1, NA, partial);
  bn_vD(nbA, bng + 3 * 128, bnb + 3 * 128, NA, partial, p2, scsh3, stream);
  g_sage<<<nbI, 256, lds_sz(0, 0), stream>>>(             // i1 = ai (no root)
      cai.rp, cai.col, h_a0, scsh1, WT(5), noi, noi, nou, nof, nou,
      (const void*)0, 0, nof, nou, bL + 5 * 128, h_i1, 1, NI, partial);
  bn_vD(nbI, bng + 4 * 128, bnb + 4 * 128, NI, partial, p2, scsh4, stream);

  // ---- Layer 2 (order: a2, i2, then p2 — p2 clobbers h_i1's region) ----
  g_sage<<<nbA, 256, lds_sz(1, 1), stream>>>(             // a2 = pa + ia (dual)
      cpa.rp, cpa.col, h_p1, scsh2, WT(7), cia.rp, cia.col, h_i1, scsh4, WT(10),
      h_a1, 0, scsh3, WT(24), cb + 256, outa, 0, NA, nop);
  g_sage<<<nbI, 256, lds_sz(0, 1), stream>>>(             // i2 = ai
      cai.rp, cai.col, h_a1, scsh3, WT(9), noi, noi, nou, nof, nou,
      h_i1, 0, scsh4, WT(20), bL + 9 * 128, outi, 0, NI, nop);
  g_sage<<<nbP, 256, lds_sz(1, 1), stream>>>(             // p2 = pp + ap (dual)
      cpp.rp, cpp.col, h_p1, scsh2, WT(6), cap.rp, cap.col, h_a1, scsh3, WT(8),
      h_p1, 0, scsh2, WT(23), cb + 128, outp, 0, NP, nop);

#undef WT
  (void)n_in; (void)ws_size; (void)out_size;
}

// Round 23
// 1513.976 us; speedup vs baseline: 2.6500x; 2.6500x over previous
//
#include <hip/hip_runtime.h>

typedef unsigned short u16;
typedef unsigned int u32;
typedef unsigned long long u64;
typedef __attribute__((ext_vector_type(4))) float f32x4;
typedef __attribute__((ext_vector_type(8))) short s16x8;

__device__ __forceinline__ float bf2f(u16 u) {
  union { u32 i; float f; } x;
  x.i = ((u32)u) << 16;
  return x.f;
}
__device__ __forceinline__ u16 f2bf(float f) {
  union { float f; u32 i; } u;
  u.f = f;
  u32 r = u.i + 0x7fffu + ((u.i >> 16) & 1u);
  return (u16)(r >> 16);
}

static inline int nblkE(long long n) { return (int)((n + 255) / 256); }

// identifier-named symbol; generic zero-fill
__global__ void HeteroGraphSAGE_52931176955955_kernel(float* p, long long n) {
  long long i = (long long)blockIdx.x * 256 + threadIdx.x;
  if (i < n) p[i] = 0.0f;
}

// ---------------- weight prep: 25 bf16 W^T mats (n-major) ----------------
__global__ void g_wprep(const float* Wl, const float* Wr, u16* wt, int total) {
  int idx = blockIdx.x * 256 + threadIdx.x;
  if (idx >= total) return;
  int w = idx >> 14;
  int r = idx & 16383;
  int n = r >> 7, k = r & 127;
  float v;
  if (w < 11) v = Wl[w * 16384 + k * 128 + n];
  else if (w < 22) v = Wr[(w - 11) * 16384 + k * 128 + n];
  else {
    int a = (w == 22) ? 2 : (w == 23) ? 6 : 7;
    int b = (w == 22) ? 4 : (w == 23) ? 8 : 10;
    v = Wr[a * 16384 + k * 128 + n] + Wr[b * 16384 + k * 128 + n];
  }
  wt[idx] = f2bf(v);
}

__global__ void g_bprep(const float* bL, float* cb) {
  int c = threadIdx.x;  // 128
  cb[c]       = bL[2 * 128 + c] + bL[4 * 128 + c];
  cb[128 + c] = bL[6 * 128 + c] + bL[8 * 128 + c];
  cb[256 + c] = bL[7 * 128 + c] + bL[10 * 128 + c];
}

__global__ void g_cvt(const float* x, u16* o, long long n4) {
  long long i = (long long)blockIdx.x * 256 + threadIdx.x;
  if (i >= n4) return;
  f32x4 v = *(const f32x4*)(x + (i << 2));
  u64 p = ((u64)f2bf(v.x)) | (((u64)f2bf(v.y)) << 16) |
          (((u64)f2bf(v.z)) << 32) | (((u64)f2bf(v.w)) << 48);
  *(u64*)(o + (i << 2)) = p;
}

// ---------------- CSR build ----------------
__global__ void g_deg(const int* e, int E, int* deg) {
  int w = blockIdx.x * 256 + threadIdx.x;
  if (w >= E) return;
  atomicAdd(deg + e[E + w], 1);
}

__global__ void g_bsum(const int* deg, int n, int C, int* bsum) {
  __shared__ int ws[4];
  int b = blockIdx.x, tid = threadIdx.x;
  int lane = tid & 63, wv = tid >> 6;
  int lo = b * C, hi = lo + C; if (hi > n) hi = n;
  int s = 0;
  for (int i = lo + tid; i < hi; i += 256) s += deg[i];
  for (int o = 32; o > 0; o >>= 1) s += __shfl_down(s, o);
  if (lane == 0) ws[wv] = s;
  __syncthreads();
  if (tid == 0) bsum[b] = ws[0] + ws[1] + ws[2] + ws[3];
}

__global__ void g_scan_write(const int* deg, int n, int C, const int* bsum,
                             int* rp, int* cur) {
  __shared__ int ws[4];
  __shared__ int bc;
  int b = blockIdx.x, tid = threadIdx.x;
  int lane = tid & 63, wv = tid >> 6;

  int v = bsum[tid];
  int s = (tid < b) ? v : 0;
  for (int o = 32; o > 0; o >>= 1) s += __shfl_down(s, o);
  if (lane == 0) ws[wv] = s;
  __syncthreads();
  if (tid == 0) bc = ws[0] + ws[1] + ws[2] + ws[3];
  __syncthreads();
  int base = bc;

  if (b == 0) {
    __syncthreads();
    int t = v;
    for (int o = 32; o > 0; o >>= 1) t += __shfl_down(t, o);
    if (lane == 0) ws[wv] = t;
    __syncthreads();
    if (tid == 0) rp[n] = ws[0] + ws[1] + ws[2] + ws[3];
  }

  int lo = b * C, hi = lo + C; if (hi > n) hi = n;
  for (int t0 = lo; t0 < hi; t0 += 256) {
    int i = t0 + tid;
    int d = (i < hi) ? deg[i] : 0;
    int x = d;
    for (int o = 1; o < 64; o <<= 1) {
      int t = __shfl_up(x, o);
      if (lane >= o) x += t;
    }
    __syncthreads();
    if (lane == 63) ws[wv] = x;
    __syncthreads();
    int wadd = 0;
    if (wv > 0) wadd += ws[0];
    if (wv > 1) wadd += ws[1];
    if (wv > 2) wadd += ws[2];
    int excl = x + wadd - d;
    if (i < hi) {
      rp[i] = base + excl;
      cur[i] = base + excl;
    }
    base += ws[0] + ws[1] + ws[2] + ws[3];
    __syncthreads();
  }
}

__global__ void g_fill(const int* e, int E, int* cur, int* col) {
  int w = blockIdx.x * 256 + threadIdx.x;
  if (w >= E) return;
  int s = e[w];
  int d = e[E + w];
  col[atomicAdd(cur + d, 1)] = s;
}

// ---------------- fused (dual-edge) gather + transform + MFMA SAGE ----------------
__device__ __forceinline__ void stage_store(u16* sm, int rr, int q, const float* acc) {
  s16x8 o;
#pragma unroll
  for (int e = 0; e < 8; ++e) o[e] = (short)f2bf(acc[e]);
  int byte = (rr << 8) + (q << 4);
  int swz = byte ^ ((rr & 7) << 4);
  *(s16x8*)((char*)sm + swz) = o;
}

__global__ __launch_bounds__(256) void g_sage(
    const int* rpA, const int* colA, const u16* srcA, const float* scshA, const u16* wtlA,
    const int* rpB, const int* colB, const u16* srcB, const float* scshB, const u16* wtlB,
    const void* root, int root_f32, const float* scshR, const u16* wtr,
    const float* bias, void* out, int out_bf, int N, float* partial) {
  extern __shared__ __align__(16) char smem[];
  const int tid = threadIdx.x;
  const int r0 = blockIdx.x * 32;
  const int nbuf = 1 + (rpB ? 1 : 0) + (root ? 1 : 0);
  u16* smA = (u16*)smem;
  u16* smB = (u16*)(smem + 8192);
  u16* smR = (u16*)(smem + (size_t)(nbuf - 1) * 8192);
  float* bs = (float*)(smem + (size_t)nbuf * 8192);
  if (partial) bs[tid] = 0.f;

  const int q  = tid & 15;
  const int c0 = q * 8;
  const int rr1 = tid >> 4;        // 0..15
  const int rr2 = rr1 + 16;        // 16..31

  // ---- gather regions: each thread owns rows rr1 & rr2 at chunk q;
  //      both j-pipelines fused -> 4 independent loads in flight ----
  for (int region = 0; region < (rpB ? 2 : 1); ++region) {
    const int* rp  = region ? rpB : rpA;
    const int* col = region ? colB : colA;
    const u16* src = region ? srcB : srcA;
    const float* scsh = region ? scshB : scshA;
    u16* sm = region ? smB : smA;
    const bool hasT = (scsh != 0);

    int row1 = r0 + rr1, row2 = r0 + rr2;
    int ja = 0, jA = 0, jb = 0, jB = 0;
    if (row1 < N) { ja = rp[row1]; jA = rp[row1 + 1]; }
    if (row2 < N) { jb = rp[row2]; jB = rp[row2 + 1]; }
    int dega = jA - ja, degb = jB - jb;
    float accA[8], accB[8];
#pragma unroll
    for (int e = 0; e < 8; ++e) { accA[e] = 0.f; accB[e] = 0.f; }

    bool va = ja < jA, vb = jb < jB;
    s16x8 ca, cb2, na, nb;
    if (va) ca  = *(const s16x8*)(src + (size_t)col[ja] * 128 + c0);
    if (vb) cb2 = *(const s16x8*)(src + (size_t)col[jb] * 128 + c0);
    while (va || vb) {
      bool van = va && (ja + 1 < jA);
      bool vbn = vb && (jb + 1 < jB);
      if (van) na = *(const s16x8*)(src + (size_t)col[ja + 1] * 128 + c0);
      if (vbn) nb = *(const s16x8*)(src + (size_t)col[jb + 1] * 128 + c0);
      if (va) {
#pragma unroll
        for (int e = 0; e < 8; ++e) {
          float f = bf2f((u16)ca[e]);
          if (hasT) f = fmaxf(f, 0.f);
          accA[e] += f;
        }
      }
      if (vb) {
#pragma unroll
        for (int e = 0; e < 8; ++e) {
          float f = bf2f((u16)cb2[e]);
          if (hasT) f = fmaxf(f, 0.f);
          accB[e] += f;
        }
      }
      ca = na; cb2 = nb; ++ja; ++jb; va = van; vb = vbn;
    }

    float invA = (dega > 0) ? 1.0f / (float)dega : 0.0f;
    float invB = (degb > 0) ? 1.0f / (float)degb : 0.0f;
#pragma unroll
    for (int e = 0; e < 8; ++e) { accA[e] *= invA; accB[e] *= invB; }
    if (hasT) {
      // mean(relu)*sc + sh  ==  per-neighbor (relu*sc+sh) averaged; guard deg==0
      if (dega > 0) {
#pragma unroll
        for (int e = 0; e < 8; ++e)
          accA[e] = accA[e] * scsh[c0 + e] + scsh[128 + c0 + e];
      }
      if (degb > 0) {
#pragma unroll
        for (int e = 0; e < 8; ++e)
          accB[e] = accB[e] * scsh[c0 + e] + scsh[128 + c0 + e];
      }
    }
    stage_store(sm, rr1, q, accA);
    stage_store(sm, rr2, q, accB);
  }

  // ---- root staging (unchanged from round 19) ----
  if (root) {
    for (int i = tid; i < 512; i += 256) {
      int rr = i >> 4, qq = i & 15;
      int row = r0 + rr;
      int cc0 = qq * 8;
      float a[8];
#pragma unroll
      for (int e = 0; e < 8; ++e) a[e] = 0.f;
      if (row < N) {
        if (root_f32) {
          const float* rp_ = (const float*)root + (size_t)row * 128 + cc0;
          f32x4 lo = *(const f32x4*)rp_;
          f32x4 hi = *(const f32x4*)(rp_ + 4);
          a[0] = lo.x; a[1] = lo.y; a[2] = lo.z; a[3] = lo.w;
          a[4] = hi.x; a[5] = hi.y; a[6] = hi.z; a[7] = hi.w;
        } else {
          s16x8 v = *(const s16x8*)((const u16*)root + (size_t)row * 128 + cc0);
#pragma unroll
          for (int e = 0; e < 8; ++e) a[e] = bf2f((u16)v[e]);
        }
        if (scshR) {
#pragma unroll
          for (int e = 0; e < 8; ++e)
            a[e] = fmaxf(a[e], 0.f) * scshR[cc0 + e] + scshR[128 + cc0 + e];
        }
      }
      stage_store(smR, rr, qq, a);
    }
  }
  __syncthreads();

  // ---- MFMA: wave wv -> row-tile m=wv>>1, col-tiles nq..nq+3 ----
  const int lane = tid & 63;
  const int wv = tid >> 6;
  const int mi = lane & 15;
  const int kg = lane >> 4;
  const int m = wv >> 1;
  const int nq = (wv & 1) * 4;
  const int arow = m * 16 + mi;
  const int abase = arow << 8;
  const int amask = (arow & 7) << 4;

  f32x4 acc4[4];
#pragma unroll
  for (int t = 0; t < 4; ++t) acc4[t] = (f32x4){0.f, 0.f, 0.f, 0.f};

#pragma unroll
  for (int kt = 0; kt < 4; ++kt) {
    int k0 = kt * 32 + kg * 8;
    int off = (abase + (k0 << 1)) ^ amask;
    s16x8 afA = *(const s16x8*)((const char*)smA + off);
    s16x8 afB, afR;
    if (rpB) afB = *(const s16x8*)((const char*)smB + off);
    if (root) afR = *(const s16x8*)((const char*)smR + off);
#pragma unroll
    for (int t = 0; t < 4; ++t) {
      int cr = (nq + t) * 16 + mi;
      s16x8 b = *(const s16x8*)(wtlA + cr * 128 + k0);
      acc4[t] = __builtin_amdgcn_mfma_f32_16x16x32_bf16(afA, b, acc4[t], 0, 0, 0);
      if (rpB) {
        s16x8 b2 = *(const s16x8*)(wtlB + cr * 128 + k0);
        acc4[t] = __builtin_amdgcn_mfma_f32_16x16x32_bf16(afB, b2, acc4[t], 0, 0, 0);
      }
      if (root) {
        s16x8 b3 = *(const s16x8*)(wtr + cr * 128 + k0);
        acc4[t] = __builtin_amdgcn_mfma_f32_16x16x32_bf16(afR, b3, acc4[t], 0, 0, 0);
      }
    }
  }

  // ---- epilogue: C/D col=lane&15, row=(lane>>4)*4+reg [m89]; fused BN stats ----
  int rbase = (lane >> 4) << 2;
#pragma unroll
  for (int t = 0; t < 4; ++t) {
    int c = (nq + t) * 16 + mi;
    float bb = bias[c];
    float s = 0.f, qq = 0.f;
#pragma unroll
    for (int reg = 0; reg < 4; ++reg) {
      int row = r0 + m * 16 + rbase + reg;
      if (row < N) {
        size_t o = (size_t)row * 128 + c;
        float v = acc4[t][reg] + bb;
        if (out_bf) ((u16*)out)[o] = f2bf(v);
        else        ((float*)out)[o] = v;
        if (partial) {
          float r = fmaxf(v, 0.f);
          s += r;
          qq += r * r;
        }
      }
    }
    if (partial) {
      s += __shfl_xor(s, 16); s += __shfl_xor(s, 32);
      qq += __shfl_xor(qq, 16); qq += __shfl_xor(qq, 32);
      if (kg == 0) {
        atomicAdd(&bs[c], s);
        atomicAdd(&bs[128 + c], qq);
      }
    }
  }
  if (partial) {
    __syncthreads();
    partial[(size_t)blockIdx.x * 256 + tid] = bs[tid];
  }
}

// ---------------- BN finalize: 2-stage partial reduce ----------------
__global__ void g_bnred(const float* partial, int nb, float* p2) {
  int tid = threadIdx.x;  // 256
  float acc = 0.f;
  for (int blk = blockIdx.x; blk < nb; blk += 64)
    acc += partial[(size_t)blk * 256 + tid];
  p2[(size_t)blockIdx.x * 256 + tid] = acc;
}

__global__ void g_bnfin(const float* p2, const float* g, const float* b,
                        float invN, float* scsh) {
  int c = threadIdx.x;  // 128
  float s = 0.f, q = 0.f;
  for (int blk = 0; blk < 64; ++blk) {
    s += p2[(size_t)blk * 256 + c];
    q += p2[(size_t)blk * 256 + 128 + c];
  }
  float m = s * invN;
  float v = q * invN - m * m;
  float sc = rsqrtf(v + 1e-5f) * g[c];
  scsh[c] = sc;
  scsh[128 + c] = b[c] - m * sc;
}

// ---------------- host ----------------
struct Csr { int* rp; int* col; };

static void build_csr(const int* e, int E, int ndst, Csr c, int* dega, int* cur,
                      int* bsum, hipStream_t st) {
  HeteroGraphSAGE_52931176955955_kernel<<<nblkE(ndst), 256, 0, st>>>((float*)dega, ndst);
  g_deg<<<nblkE(E), 256, 0, st>>>(e, E, dega);
  int C = (ndst + 255) / 256;
  g_bsum<<<256, 256, 0, st>>>(dega, ndst, C, bsum);
  g_scan_write<<<256, 256, 0, st>>>(dega, ndst, C, bsum, c.rp, cur);
  g_fill<<<nblkE(E), 256, 0, st>>>(e, E, cur, c.col);
}

static void bn_vE(int nb, const float* g, const float* b, int n,
                  float* partial, float* p2, float* scsh, hipStream_t st) {
  g_bnred<<<64, 256, 0, st>>>(partial, nb, p2);
  g_bnfin<<<1, 128, 0, st>>>(p2, g, b, 1.0f / (float)n, scsh);
}

extern "C" void kernel_launch(void* const* d_in, const int* in_sizes, int n_in,
                              void* d_out, int out_size, void* d_ws, size_t ws_size,
                              hipStream_t stream) {
  const float* x_paper  = (const float*)d_in[0];
  const float* x_author = (const float*)d_in[1];
  const int* e_pp = (const int*)d_in[3];
  const int* e_pa = (const int*)d_in[4];
  const int* e_ap = (const int*)d_in[5];
  const int* e_ai = (const int*)d_in[6];
  const int* e_ia = (const int*)d_in[7];
  const float* Wl  = (const float*)d_in[8];
  const float* bL  = (const float*)d_in[9];
  const float* Wr  = (const float*)d_in[10];
  const float* bng = (const float*)d_in[11];
  const float* bnb = (const float*)d_in[12];

  const int NP = in_sizes[0] / 128;
  const int NA = in_sizes[1] / 128;
  const int NI = in_sizes[2] / 128;
  const int Epp = in_sizes[3] / 2;
  const int Epa = in_sizes[4] / 2;
  const int Eap = in_sizes[5] / 2;
  const int Eai = in_sizes[6] / 2;
  const int Eia = in_sizes[7] / 2;

  const int nbP = (NP + 31) / 32;
  const int nbA = (NA + 31) / 32;
  const int nbI = (NI + 31) / 32;

  // ws (~160 MB)
  char* ws = (char*)d_ws;
  size_t off = 0;
  u16* xp   = (u16*)(ws + off);   off += (size_t)NP * 256;
  u16* h_p1 = (u16*)(ws + off);   off += (size_t)NP * 256;
  u16* h_a1 = (u16*)(ws + off);   off += (size_t)NA * 256;
  u16* wt   = (u16*)(ws + off);   off += (size_t)25 * 16384 * 2;
  Csr cpp; cpp.rp = (int*)(ws + off); off += (size_t)(NP + 1) * 4;
  Csr cpa; cpa.rp = (int*)(ws + off); off += (size_t)(NA + 1) * 4;
  Csr cap; cap.rp = (int*)(ws + off); off += (size_t)(NP + 1) * 4;
  Csr cai; cai.rp = (int*)(ws + off); off += (size_t)(NI + 1) * 4;
  Csr cia; cia.rp = (int*)(ws + off); off += (size_t)(NA + 1) * 4;
  cpp.col = (int*)(ws + off); off += (size_t)Epp * 4;
  cpa.col = (int*)(ws + off); off += (size_t)Epa * 4;
  cap.col = (int*)(ws + off); off += (size_t)Eap * 4;
  cai.col = (int*)(ws + off); off += (size_t)Eai * 4;
  cia.col = (int*)(ws + off); off += (size_t)Eia * 4;
  int* dega = (int*)(ws + off);      off += (size_t)NP * 4;
  int* cur  = (int*)(ws + off);      off += (size_t)NP * 4;
  int* bsum = (int*)(ws + off);      off += 1024;
  float* partial = (float*)(ws + off); off += (size_t)nbP * 1024;
  float* p2    = (float*)(ws + off); off += 64 * 1024;
  float* scsh0 = (float*)(ws + off); off += 1024;
  float* scsh1 = (float*)(ws + off); off += 1024;
  float* scsh2 = (float*)(ws + off); off += 1024;
  float* scsh3 = (float*)(ws + off); off += 1024;
  float* scsh4 = (float*)(ws + off); off += 1024;
  float* cb    = (float*)(ws + off); off += 3 * 512;

  // d_out fp32 regions: p2 | a2 | i2; raw bf16 hiddens parked inside
  float* outp = (float*)d_out;
  float* outa = outp + (size_t)NP * 128;
  float* outi = outa + (size_t)NA * 128;
  u16* h_p0 = (u16*)outp;
  u16* h_a0 = (u16*)outa;
  u16* h_i1 = (u16*)outp + (size_t)NP * 128;

  g_wprep<<<nblkE(25 * 16384), 256, 0, stream>>>(Wl, Wr, wt, 25 * 16384);
  g_bprep<<<1, 128, 0, stream>>>(bL, cb);
  g_cvt<<<nblkE((long long)NP * 32), 256, 0, stream>>>(x_paper, xp, (long long)NP * 32);
  build_csr(e_pp, Epp, NP, cpp, dega, cur, bsum, stream);
  build_csr(e_pa, Epa, NA, cpa, dega, cur, bsum, stream);
  build_csr(e_ap, Eap, NP, cap, dega, cur, bsum, stream);
  build_csr(e_ai, Eai, NI, cai, dega, cur, bsum, stream);
  build_csr(e_ia, Eia, NA, cia, dega, cur, bsum, stream);

  const float* nof = (const float*)0;
  const int* noi = (const int*)0;
  const u16* nou = (const u16*)0;
  float* nop = (float*)0;

#define WT(i) (wt + (size_t)(i) * 16384)

  // ---- Layer 0 (raw hidden + fused BN stats) ----
  g_sage<<<nbP, 256, 2 * 8192 + 1024, stream>>>(
      cpp.rp, cpp.col, xp, nof, WT(0), noi, noi, nou, nof, nou,
      xp, 0, nof, WT(11), bL + 0 * 128, h_p0, 1, NP, partial);
  bn_vE(nbP, bng + 0 * 128, bnb + 0 * 128, NP, partial, p2, scsh0, stream);
  g_sage<<<nbA, 256, 2 * 8192 + 1024, stream>>>(
      cpa.rp, cpa.col, xp, nof, WT(1), noi, noi, nou, nof, nou,
      x_author, 1, nof, WT(12), bL + 1 * 128, h_a0, 1, NA, partial);
  bn_vE(nbA, bng + 1 * 128, bnb + 1 * 128, NA, partial, p2, scsh1, stream);

  // ---- Layer 1 ----
  g_sage<<<nbP, 256, 3 * 8192 + 1024, stream>>>(          // p1 = pp + ap (dual)
      cpp.rp, cpp.col, h_p0, scsh0, WT(2), cap.rp, cap.col, h_a0, scsh1, WT(4),
      h_p0, 0, scsh0, WT(22), cb, h_p1, 1, NP, partial);
  bn_vE(nbP, bng + 2 * 128, bnb + 2 * 128, NP, partial, p2, scsh2, stream);
  g_sage<<<nbA, 256, 2 * 8192 + 1024, stream>>>(          // a1 = pa
      cpa.rp, cpa.col, h_p0, scsh0, WT(3), noi, noi, nou, nof, nou,
      h_a0, 0, scsh1, WT(14), bL + 3 * 128, h_a1, 1, NA, partial);
  bn_vE(nbA, bng + 3 * 128, bnb + 3 * 128, NA, partial, p2, scsh3, stream);
  g_sage<<<nbI, 256, 1 * 8192 + 1024, stream>>>(          // i1 = ai (no root)
      cai.rp, cai.col, h_a0, scsh1, WT(5), noi, noi, nou, nof, nou,
      (const void*)0, 0, nof, nou, bL + 5 * 128, h_i1, 1, NI, partial);
  bn_vE(nbI, bng + 4 * 128, bnb + 4 * 128, NI, partial, p2, scsh4, stream);

  // ---- Layer 2 (order: a2, i2, then p2 — p2 clobbers h_i1's region) ----
  g_sage<<<nbA, 256, 3 * 8192, stream>>>(                 // a2 = pa + ia (dual)
      cpa.rp, cpa.col, h_p1, scsh2, WT(7), cia.rp, cia.col, h_i1, scsh4, WT(10),
      h_a1, 0, scsh3, WT(24), cb + 256, outa, 0, NA, nop);
  g_sage<<<nbI, 256, 2 * 8192, stream>>>(                 // i2 = ai
      cai.rp, cai.col, h_a1, scsh3, WT(9), noi, noi, nou, nof, nou,
      h_i1, 0, scsh4, WT(20), bL + 9 * 128, outi, 0, NI, nop);
  g_sage<<<nbP, 256, 3 * 8192, stream>>>(                 // p2 = pp + ap (dual)
      cpp.rp, cpp.col, h_p1, scsh2, WT(6), cap.rp, cap.col, h_a1, scsh3, WT(8),
      h_p1, 0, scsh2, WT(23), cb + 128, outp, 0, NP, nop);

#undef WT
  (void)n_in; (void)ws_size; (void)out_size;
}

// Round 24
// 1426.413 us; speedup vs baseline: 2.8127x; 1.0614x over previous
//
#include <hip/hip_runtime.h>

typedef unsigned short u16;
typedef unsigned int u32;
typedef unsigned long long u64;
typedef __attribute__((ext_vector_type(4))) float f32x4;
typedef __attribute__((ext_vector_type(8))) short s16x8;

__device__ __forceinline__ float bf2f(u16 u) {
  union { u32 i; float f; } x;
  x.i = ((u32)u) << 16;
  return x.f;
}
__device__ __forceinline__ u16 f2bf(float f) {
  union { float f; u32 i; } u;
  u.f = f;
  u32 r = u.i + 0x7fffu + ((u.i >> 16) & 1u);
  return (u16)(r >> 16);
}

static inline int nblkF(long long n) { return (int)((n + 255) / 256); }

// identifier-named symbol; generic zero-fill
__global__ void HeteroGraphSAGE_52931176955955_kernel(float* p, long long n) {
  long long i = (long long)blockIdx.x * 256 + threadIdx.x;
  if (i < n) p[i] = 0.0f;
}

// ---------------- weight prep: 25 bf16 W^T mats (n-major) ----------------
__global__ void g_wprep(const float* Wl, const float* Wr, u16* wt, int total) {
  int idx = blockIdx.x * 256 + threadIdx.x;
  if (idx >= total) return;
  int w = idx >> 14;
  int r = idx & 16383;
  int n = r >> 7, k = r & 127;
  float v;
  if (w < 11) v = Wl[w * 16384 + k * 128 + n];
  else if (w < 22) v = Wr[(w - 11) * 16384 + k * 128 + n];
  else {
    int a = (w == 22) ? 2 : (w == 23) ? 6 : 7;
    int b = (w == 22) ? 4 : (w == 23) ? 8 : 10;
    v = Wr[a * 16384 + k * 128 + n] + Wr[b * 16384 + k * 128 + n];
  }
  wt[idx] = f2bf(v);
}

__global__ void g_bprep(const float* bL, float* cb) {
  int c = threadIdx.x;  // 128
  cb[c]       = bL[2 * 128 + c] + bL[4 * 128 + c];
  cb[128 + c] = bL[6 * 128 + c] + bL[8 * 128 + c];
  cb[256 + c] = bL[7 * 128 + c] + bL[10 * 128 + c];
}

__global__ void g_cvt(const float* x, u16* o, long long n4) {
  long long i = (long long)blockIdx.x * 256 + threadIdx.x;
  if (i >= n4) return;
  f32x4 v = *(const f32x4*)(x + (i << 2));
  u64 p = ((u64)f2bf(v.x)) | (((u64)f2bf(v.y)) << 16) |
          (((u64)f2bf(v.z)) << 32) | (((u64)f2bf(v.w)) << 48);
  *(u64*)(o + (i << 2)) = p;
}

// ---------------- batched CSR build (all 5 edge types at once) ----------------
struct Seg { const int* e; int E; int eoff; int roff; };

__device__ __forceinline__ Seg pick_seg(Seg s0, Seg s1, Seg s2, Seg s3, Seg s4, int w) {
  if (w >= s4.eoff) return s4;
  if (w >= s3.eoff) return s3;
  if (w >= s2.eoff) return s2;
  if (w >= s1.eoff) return s1;
  return s0;
}

__global__ void g_deg5(Seg s0, Seg s1, Seg s2, Seg s3, Seg s4, int Eall, int* deg) {
  int w = blockIdx.x * 256 + threadIdx.x;
  if (w >= Eall) return;
  Seg s = pick_seg(s0, s1, s2, s3, s4, w);
  int i = w - s.eoff;
  atomicAdd(deg + s.roff + s.e[s.E + i], 1);
}

__global__ void g_fill5(Seg s0, Seg s1, Seg s2, Seg s3, Seg s4, int Eall,
                        int* cur, int* col) {
  int w = blockIdx.x * 256 + threadIdx.x;
  if (w >= Eall) return;
  Seg s = pick_seg(s0, s1, s2, s3, s4, w);
  int i = w - s.eoff;
  int src = s.e[i];
  int d = s.e[s.E + i];
  col[atomicAdd(cur + s.roff + d, 1)] = src;
}

__global__ void g_bsum(const int* deg, int n, int C, int* bsum) {
  __shared__ int ws[4];
  int b = blockIdx.x, tid = threadIdx.x;
  int lane = tid & 63, wv = tid >> 6;
  int lo = b * C, hi = lo + C; if (hi > n) hi = n;
  int s = 0;
  for (int i = lo + tid; i < hi; i += 256) s += deg[i];
  for (int o = 32; o > 0; o >>= 1) s += __shfl_down(s, o);
  if (lane == 0) ws[wv] = s;
  __syncthreads();
  if (tid == 0) bsum[b] = ws[0] + ws[1] + ws[2] + ws[3];
}

__global__ void g_scan_write(const int* deg, int n, int C, const int* bsum,
                             int* rp, int* cur) {
  __shared__ int ws[4];
  __shared__ int bc;
  int b = blockIdx.x, tid = threadIdx.x;
  int lane = tid & 63, wv = tid >> 6;

  int v = bsum[tid];
  int s = (tid < b) ? v : 0;
  for (int o = 32; o > 0; o >>= 1) s += __shfl_down(s, o);
  if (lane == 0) ws[wv] = s;
  __syncthreads();
  if (tid == 0) bc = ws[0] + ws[1] + ws[2] + ws[3];
  __syncthreads();
  int base = bc;

  if (b == 0) {
    __syncthreads();
    int t = v;
    for (int o = 32; o > 0; o >>= 1) t += __shfl_down(t, o);
    if (lane == 0) ws[wv] = t;
    __syncthreads();
    if (tid == 0) rp[n] = ws[0] + ws[1] + ws[2] + ws[3];
  }

  int lo = b * C, hi = lo + C; if (hi > n) hi = n;
  for (int t0 = lo; t0 < hi; t0 += 256) {
    int i = t0 + tid;
    int d = (i < hi) ? deg[i] : 0;
    int x = d;
    for (int o = 1; o < 64; o <<= 1) {
      int t = __shfl_up(x, o);
      if (lane >= o) x += t;
    }
    __syncthreads();
    if (lane == 63) ws[wv] = x;
    __syncthreads();
    int wadd = 0;
    if (wv > 0) wadd += ws[0];
    if (wv > 1) wadd += ws[1];
    if (wv > 2) wadd += ws[2];
    int excl = x + wadd - d;
    if (i < hi) {
      rp[i] = base + excl;
      cur[i] = base + excl;
    }
    base += ws[0] + ws[1] + ws[2] + ws[3];
    __syncthreads();
  }
}

// ---------------- fused (dual-edge) gather + transform + MFMA SAGE ----------------
// (round-19 structure: per-(row,chunk) tasks, 2-deep pipeline — proven best)
__device__ __forceinline__ void stage_store(u16* sm, int rr, int q, const float* acc) {
  s16x8 o;
#pragma unroll
  for (int e = 0; e < 8; ++e) o[e] = (short)f2bf(acc[e]);
  int byte = (rr << 8) + (q << 4);
  int swz = byte ^ ((rr & 7) << 4);
  *(s16x8*)((char*)sm + swz) = o;
}

__global__ __launch_bounds__(256) void g_sage(
    const int* rpA, const int* colA, const u16* srcA, const float* scshA, const u16* wtlA,
    const int* rpB, const int* colB, const u16* srcB, const float* scshB, const u16* wtlB,
    const void* root, int root_f32, const float* scshR, const u16* wtr,
    const float* bias, void* out, int out_bf, int N, float* partial) {
  extern __shared__ __align__(16) char smem[];
  const int tid = threadIdx.x;
  const int r0 = blockIdx.x * 32;
  const int nbuf = 1 + (rpB ? 1 : 0) + (root ? 1 : 0);
  u16* smA = (u16*)smem;
  u16* smB = (u16*)(smem + 8192);
  u16* smR = (u16*)(smem + (size_t)(nbuf - 1) * 8192);
  float* bs = (float*)(smem + (size_t)nbuf * 8192);
  if (partial) bs[tid] = 0.f;

  for (int i = tid; i < nbuf * 512; i += 256) {
    int region = i >> 9;
    int t = i & 511;
    int rr = t >> 4, q = t & 15;
    int row = r0 + rr;
    int c0 = q * 8;
    float acc[8];
#pragma unroll
    for (int e = 0; e < 8; ++e) acc[e] = 0.f;

    bool isRoot = root && (region == nbuf - 1);
    if (isRoot) {
      if (row < N) {
        if (root_f32) {
          const float* rp_ = (const float*)root + (size_t)row * 128 + c0;
          f32x4 lo = *(const f32x4*)rp_;
          f32x4 hi = *(const f32x4*)(rp_ + 4);
          acc[0] = lo.x; acc[1] = lo.y; acc[2] = lo.z; acc[3] = lo.w;
          acc[4] = hi.x; acc[5] = hi.y; acc[6] = hi.z; acc[7] = hi.w;
        } else {
          s16x8 v = *(const s16x8*)((const u16*)root + (size_t)row * 128 + c0);
#pragma unroll
          for (int e = 0; e < 8; ++e) acc[e] = bf2f((u16)v[e]);
        }
        if (scshR) {
#pragma unroll
          for (int e = 0; e < 8; ++e)
            acc[e] = fmaxf(acc[e], 0.f) * scshR[c0 + e] + scshR[128 + c0 + e];
        }
      }
      stage_store(smR, rr, q, acc);
    } else {
      const int* rp = (region == 0) ? rpA : rpB;
      const int* col = (region == 0) ? colA : colB;
      const u16* src = (region == 0) ? srcA : srcB;
      const float* scsh = (region == 0) ? scshA : scshB;
      if (row < N) {
        int j0 = rp[row], j1 = rp[row + 1];
        if (scsh) {
          float sc[8], sh[8];
#pragma unroll
          for (int e = 0; e < 8; ++e) { sc[e] = scsh[c0 + e]; sh[e] = scsh[128 + c0 + e]; }
          if (j0 < j1) {
            s16x8 vc = *(const s16x8*)(src + (size_t)col[j0] * 128 + c0);
            for (int j = j0 + 1; j < j1; ++j) {
              s16x8 vn = *(const s16x8*)(src + (size_t)col[j] * 128 + c0);
#pragma unroll
              for (int e = 0; e < 8; ++e)
                acc[e] += fmaxf(bf2f((u16)vc[e]), 0.f) * sc[e] + sh[e];
              vc = vn;
            }
#pragma unroll
            for (int e = 0; e < 8; ++e)
              acc[e] += fmaxf(bf2f((u16)vc[e]), 0.f) * sc[e] + sh[e];
          }
        } else {
          if (j0 < j1) {
            s16x8 vc = *(const s16x8*)(src + (size_t)col[j0] * 128 + c0);
            for (int j = j0 + 1; j < j1; ++j) {
              s16x8 vn = *(const s16x8*)(src + (size_t)col[j] * 128 + c0);
#pragma unroll
              for (int e = 0; e < 8; ++e) acc[e] += bf2f((u16)vc[e]);
              vc = vn;
            }
#pragma unroll
            for (int e = 0; e < 8; ++e) acc[e] += bf2f((u16)vc[e]);
          }
        }
        float inv = 1.0f / fmaxf((float)(j1 - j0), 1.0f);
#pragma unroll
        for (int e = 0; e < 8; ++e) acc[e] *= inv;
      }
      stage_store((region == 0) ? smA : smB, rr, q, acc);
    }
  }
  __syncthreads();

  // ---- MFMA: wave wv -> row-tile m=wv>>1, col-tiles nq..nq+3 ----
  const int lane = tid & 63;
  const int wv = tid >> 6;
  const int mi = lane & 15;
  const int kg = lane >> 4;
  const int m = wv >> 1;
  const int nq = (wv & 1) * 4;
  const int arow = m * 16 + mi;
  const int abase = arow << 8;
  const int amask = (arow & 7) << 4;

  f32x4 acc4[4];
#pragma unroll
  for (int t = 0; t < 4; ++t) acc4[t] = (f32x4){0.f, 0.f, 0.f, 0.f};

#pragma unroll
  for (int kt = 0; kt < 4; ++kt) {
    int k0 = kt * 32 + kg * 8;
    int off = (abase + (k0 << 1)) ^ amask;
    s16x8 afA = *(const s16x8*)((const char*)smA + off);
    s16x8 afB, afR;
    if (rpB) afB = *(const s16x8*)((const char*)smB + off);
    if (root) afR = *(const s16x8*)((const char*)smR + off);
#pragma unroll
    for (int t = 0; t < 4; ++t) {
      int cr = (nq + t) * 16 + mi;
      s16x8 b = *(const s16x8*)(wtlA + cr * 128 + k0);
      acc4[t] = __builtin_amdgcn_mfma_f32_16x16x32_bf16(afA, b, acc4[t], 0, 0, 0);
      if (rpB) {
        s16x8 b2 = *(const s16x8*)(wtlB + cr * 128 + k0);
        acc4[t] = __builtin_amdgcn_mfma_f32_16x16x32_bf16(afB, b2, acc4[t], 0, 0, 0);
      }
      if (root) {
        s16x8 b3 = *(const s16x8*)(wtr + cr * 128 + k0);
        acc4[t] = __builtin_amdgcn_mfma_f32_16x16x32_bf16(afR, b3, acc4[t], 0, 0, 0);
      }
    }
  }

  // ---- epilogue: C/D col=lane&15, row=(lane>>4)*4+reg [m89]; fused BN stats ----
  int rbase = (lane >> 4) << 2;
#pragma unroll
  for (int t = 0; t < 4; ++t) {
    int c = (nq + t) * 16 + mi;
    float bb = bias[c];
    float s = 0.f, q = 0.f;
#pragma unroll
    for (int reg = 0; reg < 4; ++reg) {
      int row = r0 + m * 16 + rbase + reg;
      if (row < N) {
        size_t o = (size_t)row * 128 + c;
        float v = acc4[t][reg] + bb;
        if (out_bf) ((u16*)out)[o] = f2bf(v);
        else        ((float*)out)[o] = v;
        if (partial) {
          float r = fmaxf(v, 0.f);
          s += r;
          q += r * r;
        }
      }
    }
    if (partial) {
      s += __shfl_xor(s, 16); s += __shfl_xor(s, 32);
      q += __shfl_xor(q, 16); q += __shfl_xor(q, 32);
      if (kg == 0) {
        atomicAdd(&bs[c], s);
        atomicAdd(&bs[128 + c], q);
      }
    }
  }
  if (partial) {
    __syncthreads();
    partial[(size_t)blockIdx.x * 256 + tid] = bs[tid];
  }
}

// ---------------- BN finalize: 2-stage partial reduce ----------------
__global__ void g_bnred(const float* partial, int nb, float* p2) {
  int tid = threadIdx.x;  // 256
  float acc = 0.f;
  for (int blk = blockIdx.x; blk < nb; blk += 64)
    acc += partial[(size_t)blk * 256 + tid];
  p2[(size_t)blockIdx.x * 256 + tid] = acc;
}

__global__ void g_bnfin(const float* p2, const float* g, const float* b,
                        float invN, float* scsh) {
  int c = threadIdx.x;  // 128
  float s = 0.f, q = 0.f;
  for (int blk = 0; blk < 64; ++blk) {
    s += p2[(size_t)blk * 256 + c];
    q += p2[(size_t)blk * 256 + 128 + c];
  }
  float m = s * invN;
  float v = q * invN - m * m;
  float sc = rsqrtf(v + 1e-5f) * g[c];
  scsh[c] = sc;
  scsh[128 + c] = b[c] - m * sc;
}

// ---------------- host ----------------
struct Csr { int* rp; int* col; };

static void bn_vF(int nb, const float* g, const float* b, int n,
                  float* partial, float* p2, float* scsh, hipStream_t st) {
  g_bnred<<<64, 256, 0, st>>>(partial, nb, p2);
  g_bnfin<<<1, 128, 0, st>>>(p2, g, b, 1.0f / (float)n, scsh);
}

extern "C" void kernel_launch(void* const* d_in, const int* in_sizes, int n_in,
                              void* d_out, int out_size, void* d_ws, size_t ws_size,
                              hipStream_t stream) {
  const float* x_paper  = (const float*)d_in[0];
  const float* x_author = (const float*)d_in[1];
  const int* e_pp = (const int*)d_in[3];
  const int* e_pa = (const int*)d_in[4];
  const int* e_ap = (const int*)d_in[5];
  const int* e_ai = (const int*)d_in[6];
  const int* e_ia = (const int*)d_in[7];
  const float* Wl  = (const float*)d_in[8];
  const float* bL  = (const float*)d_in[9];
  const float* Wr  = (const float*)d_in[10];
  const float* bng = (const float*)d_in[11];
  const float* bnb = (const float*)d_in[12];

  const int NP = in_sizes[0] / 128;
  const int NA = in_sizes[1] / 128;
  const int NI = in_sizes[2] / 128;
  const int Epp = in_sizes[3] / 2;
  const int Epa = in_sizes[4] / 2;
  const int Eap = in_sizes[5] / 2;
  const int Eai = in_sizes[6] / 2;
  const int Eia = in_sizes[7] / 2;

  const int nbP = (NP + 31) / 32;
  const int nbA = (NA + 31) / 32;
  const int nbI = (NI + 31) / 32;

  // batched CSR geometry
  const int R = 2 * NP + 2 * NA + NI;
  const long long Eall = (long long)Epp + Epa + Eap + Eai + Eia;

  // ws (~170 MB)
  char* ws = (char*)d_ws;
  size_t off = 0;
  u16* xp   = (u16*)(ws + off);   off += (size_t)NP * 256;
  u16* h_p1 = (u16*)(ws + off);   off += (size_t)NP * 256;
  u16* h_a1 = (u16*)(ws + off);   off += (size_t)NA * 256;
  u16* wt   = (u16*)(ws + off);   off += (size_t)25 * 16384 * 2;
  int* rp_all  = (int*)(ws + off);   off += (size_t)(R + 1) * 4;
  int* col_all = (int*)(ws + off);   off += (size_t)Eall * 4;
  int* dega    = (int*)(ws + off);   off += (size_t)R * 4;
  int* cur     = (int*)(ws + off);   off += (size_t)R * 4;
  int* bsum    = (int*)(ws + off);   off += 1024;
  float* partial = (float*)(ws + off); off += (size_t)nbP * 1024;
  float* p2    = (float*)(ws + off); off += 64 * 1024;
  float* scsh0 = (float*)(ws + off); off += 1024;
  float* scsh1 = (float*)(ws + off); off += 1024;
  float* scsh2 = (float*)(ws + off); off += 1024;
  float* scsh3 = (float*)(ws + off); off += 1024;
  float* scsh4 = (float*)(ws + off); off += 1024;
  float* cb    = (float*)(ws + off); off += 3 * 512;

  // per-type CSR views into the global arrays (rp values are global col offsets)
  Csr cpp; cpp.rp = rp_all;                      cpp.col = col_all;
  Csr cpa; cpa.rp = rp_all + NP;                 cpa.col = col_all;
  Csr cap; cap.rp = rp_all + NP + NA;            cap.col = col_all;
  Csr cai; cai.rp = rp_all + 2 * NP + NA;        cai.col = col_all;
  Csr cia; cia.rp = rp_all + 2 * NP + NA + NI;   cia.col = col_all;

  // d_out fp32 regions: p2 | a2 | i2; raw bf16 hiddens parked inside
  float* outp = (float*)d_out;
  float* outa = outp + (size_t)NP * 128;
  float* outi = outa + (size_t)NA * 128;
  u16* h_p0 = (u16*)outp;
  u16* h_a0 = (u16*)outa;
  u16* h_i1 = (u16*)outp + (size_t)NP * 128;

  g_wprep<<<nblkF(25 * 16384), 256, 0, stream>>>(Wl, Wr, wt, 25 * 16384);
  g_bprep<<<1, 128, 0, stream>>>(bL, cb);
  g_cvt<<<nblkF((long long)NP * 32), 256, 0, stream>>>(x_paper, xp, (long long)NP * 32);

  // ---- batched CSR build: 5 launches total ----
  Seg s0 = { e_pp, Epp, 0, 0 };
  Seg s1 = { e_pa, Epa, Epp, NP };
  Seg s2 = { e_ap, Eap, Epp + Epa, NP + NA };
  Seg s3 = { e_ai, Eai, Epp + Epa + Eap, 2 * NP + NA };
  Seg s4 = { e_ia, Eia, Epp + Epa + Eap + Eai, 2 * NP + NA + NI };
  HeteroGraphSAGE_52931176955955_kernel<<<nblkF(R), 256, 0, stream>>>((float*)dega, R);
  g_deg5<<<nblkF(Eall), 256, 0, stream>>>(s0, s1, s2, s3, s4, (int)Eall, dega);
  int C = (R + 255) / 256;
  g_bsum<<<256, 256, 0, stream>>>(dega, R, C, bsum);
  g_scan_write<<<256, 256, 0, stream>>>(dega, R, C, bsum, rp_all, cur);
  g_fill5<<<nblkF(Eall), 256, 0, stream>>>(s0, s1, s2, s3, s4, (int)Eall, cur, col_all);

  const float* nof = (const float*)0;
  const int* noi = (const int*)0;
  const u16* nou = (const u16*)0;
  float* nop = (float*)0;

#define WT(i) (wt + (size_t)(i) * 16384)

  // ---- Layer 0 (raw hidden + fused BN stats) ----
  g_sage<<<nbP, 256, 2 * 8192 + 1024, stream>>>(
      cpp.rp, cpp.col, xp, nof, WT(0), noi, noi, nou, nof, nou,
      xp, 0, nof, WT(11), bL + 0 * 128, h_p0, 1, NP, partial);
  bn_vF(nbP, bng + 0 * 128, bnb + 0 * 128, NP, partial, p2, scsh0, stream);
  g_sage<<<nbA, 256, 2 * 8192 + 1024, stream>>>(
      cpa.rp, cpa.col, xp, nof, WT(1), noi, noi, nou, nof, nou,
      x_author, 1, nof, WT(12), bL + 1 * 128, h_a0, 1, NA, partial);
  bn_vF(nbA, bng + 1 * 128, bnb + 1 * 128, NA, partial, p2, scsh1, stream);

  // ---- Layer 1 ----
  g_sage<<<nbP, 256, 3 * 8192 + 1024, stream>>>(          // p1 = pp + ap (dual)
      cpp.rp, cpp.col, h_p0, scsh0, WT(2), cap.rp, cap.col, h_a0, scsh1, WT(4),
      h_p0, 0, scsh0, WT(22), cb, h_p1, 1, NP, partial);
  bn_vF(nbP, bng + 2 * 128, bnb + 2 * 128, NP, partial, p2, scsh2, stream);
  g_sage<<<nbA, 256, 2 * 8192 + 1024, stream>>>(          // a1 = pa
      cpa.rp, cpa.col, h_p0, scsh0, WT(3), noi, noi, nou, nof, nou,
      h_a0, 0, scsh1, WT(14), bL + 3 * 128, h_a1, 1, NA, partial);
  bn_vF(nbA, bng + 3 * 128, bnb + 3 * 128, NA, partial, p2, scsh3, stream);
  g_sage<<<nbI, 256, 1 * 8192 + 1024, stream>>>(          // i1 = ai (no root)
      cai.rp, cai.col, h_a0, scsh1, WT(5), noi, noi, nou, nof, nou,
      (const void*)0, 0, nof, nou, bL + 5 * 128, h_i1, 1, NI, partial);
  bn_vF(nbI, bng + 4 * 128, bnb + 4 * 128, NI, partial, p2, scsh4, stream);

  // ---- Layer 2 (order: a2, i2, then p2 — p2 clobbers h_i1's region) ----
  g_sage<<<nbA, 256, 3 * 8192, stream>>>(                 // a2 = pa + ia (dual)
      cpa.rp, cpa.col, h_p1, scsh2, WT(7), cia.rp, cia.col, h_i1, scsh4, WT(10),
      h_a1, 0, scsh3, WT(24), cb + 256, outa, 0, NA, nop);
  g_sage<<<nbI, 256, 2 * 8192, stream>>>(                 // i2 = ai
      cai.rp, cai.col, h_a1, scsh3, WT(9), noi, noi, nou, nof, nou,
      h_i1, 0, scsh4, WT(20), bL + 9 * 128, outi, 0, NI, nop);
  g_sage<<<nbP, 256, 3 * 8192, stream>>>(                 // p2 = pp + ap (dual)
      cpp.rp, cpp.col, h_p1, scsh2, WT(6), cap.rp, cap.col, h_a1, scsh3, WT(8),
      h_p1, 0, scsh2, WT(23), cb + 128, outp, 0, NP, nop);

#undef WT
  (void)n_in; (void)ws_size; (void)out_size;
}